// Round 11
// baseline (656.616 us; speedup 1.0000x reference)
//
#include <hip/hip_runtime.h>

// Frobenius_71975061946522 — R11: R9 skeleton (block-level flags, the proven
// lockstep structure) + fused update/staging + equality polls (no memset).
//
// X (4096x4096 fp32, 64 MB) lives in the unified VGPR/AGPR file for all 20
// iterations: 256 blocks x 1024 threads (1 block/CU, forced by 84 KB LDS);
// thread t of block b holds X[16b+r][4t..4t+3], r=0..15.
//
// R10 lesson: per-WAVE flag publish removes the block-sync rate-limiters ->
// grid loses lockstep, spins lengthen 4x, coherent poll-loads storm the TCC
// (FETCH 120->450 MB, WRITE 230->750 MB). Block-level flags after a block
// sync keep all 256 blocks in phase; keep them.
//
// Dataflow per iteration (zero barriers, zero fences, zero RMW):
//   phase2: block b polls flag1[src]==k+1 (16 lanes/wave x 16 waves cover
//           all 256 sources), loads colpart[src][16b..16b+16) via b64
//           relaxed agent atomics, folds 256->1 (wave butterfly + wql),
//           wave 0 publishes col_out[16b..16b+16), then flag2[b]=k+1.
//   phase3: block b polls flag2[src]==k+1 (wave w needs exactly sources
//           16w..16w+16 for its threads' col_out[4t..4t+3]), loads col
//           sums, redundant per-block grand total, then FUSED: relu-update
//           of x[] + next iteration's column/row partials in the same loop,
//           colpart stores, wave-drain, block sync, flag1[b]=k+2.
//
// Equality-poll safety (single writer per flag, one value per generation):
//   flag1[b]=k+2 requires b's phase3-k, which polls flag2[*]==k+1, set by
//   each block only after its sync(A)-k, which requires ALL its waves'
//   phase2-k polls flag1[*]==k+1 to have PASSED. So every consumer observed
//   flag1[b]==k+1 before it can be overwritten -> no missed values. Same
//   chain one level down for flag2. Initial 0xAA poison matches no target.
//
// WAR safety (single-buffered colpart/col_out, as proven R9/R10):
//   colpart[b][4t..4t+3] rewritten at k+1 only after thread t passed its
//   flag2[t>>2]==k+1 poll, set after that block's phase2-k reads (sync(A)-
//   ordered). col_out[16b..) rewritten at k+1 only after sync(A)-(k+1),
//   gated through every block's flag1==k+2, each published after its
//   phase3-k col_out reads in program order.

#define NN    4096
#define NV4   1024
#define RPB   16
#define NBLK  256
#define ITERS 20
#define INV_N (1.0f / 4096.0f)
#define PSTR  21            // part[] stride: odd (conflict-free), 84 KB LDS
                            // forces exactly 1 block/CU

typedef unsigned long long u64;
typedef float f32x4 __attribute__((ext_vector_type(4)));

__device__ __forceinline__ void st_atomic_f32x2(float* p, float a, float b) {
    u64 u = (u64)__float_as_uint(a) | ((u64)__float_as_uint(b) << 32);
    __hip_atomic_store((u64*)p, u, __ATOMIC_RELAXED, __HIP_MEMORY_SCOPE_AGENT);
}
__device__ __forceinline__ float2 ld_atomic_f32x2(const float* p) {
    u64 u = __hip_atomic_load((const u64*)p, __ATOMIC_RELAXED,
                              __HIP_MEMORY_SCOPE_AGENT);
    return make_float2(__uint_as_float((unsigned)u),
                       __uint_as_float((unsigned)(u >> 32)));
}
__device__ __forceinline__ void set_flag(u64* f, u64 v) {
    __hip_atomic_store(f, v, __ATOMIC_RELAXED, __HIP_MEMORY_SCOPE_AGENT);
}
// Equality poll: initial 0xAA.. poison never matches a target in 1..21.
__device__ __forceinline__ void poll_eq(const u64* f, u64 tgt) {
    while (__hip_atomic_load(f, __ATOMIC_RELAXED, __HIP_MEMORY_SCOPE_AGENT) != tgt)
        __builtin_amdgcn_s_sleep(1);
}

__global__ __launch_bounds__(1024, 4)
void persist10(const float* __restrict__ X0, float* __restrict__ Xout,
               float* __restrict__ colpart,   // [NBLK][NN]
               float* __restrict__ col_out,   // [NN]
               u64* __restrict__ flag1,       // [NBLK] stride 8 (64 B)
               u64* __restrict__ flag2)       // [NBLK] stride 8
{
    const int t    = threadIdx.x;
    const int wave = t >> 6;
    const int lane = t & 63;
    const int b    = blockIdx.x;
    const int row0 = b * RPB;

    __shared__ float part[1024 * PSTR];      // row-partial transpose (~84 KB)
    __shared__ f32x4 wql[64];                // per-wave column-partial quads
    __shared__ float rowsum[RPB];
    __shared__ float sred[16];

    // Load this thread's 16 float4 of X into registers.
    f32x4 x[RPB];
    const f32x4* x0 = (const f32x4*)X0;
    #pragma unroll
    for (int r = 0; r < RPB; ++r)
        x[r] = x0[(size_t)(row0 + r) * NV4 + t];

    // ---- prologue: stage iter-0 column/row partials ----
    {
        f32x4 cacc = x[0];
        #pragma unroll
        for (int r = 1; r < RPB; ++r) cacc += x[r];
        float* cp = colpart + (size_t)b * NN + 4 * t;
        st_atomic_f32x2(cp,     cacc.x, cacc.y);
        st_atomic_f32x2(cp + 2, cacc.z, cacc.w);
        #pragma unroll
        for (int r = 0; r < RPB; ++r)
            part[t * PSTR + r] = (x[r].x + x[r].y) + (x[r].z + x[r].w);
        asm volatile("s_waitcnt vmcnt(0)" ::: "memory");  // own stores drained
        __syncthreads();                                   // all waves drained
        if (t == 0) set_flag(flag1 + (size_t)b * 8, 1);
        float v = 0.f;
        #pragma unroll
        for (int kk = 0; kk < 16; ++kk)
            v += part[(lane + 64 * kk) * PSTR + wave];
        #pragma unroll
        for (int m = 1; m < 64; m <<= 1) v += __shfl_xor(v, m, 64);
        if (lane == 0) rowsum[wave] = v;
        // rowsum visibility for the update is covered by sync (A)/(B) below
    }

    for (unsigned k = 0; k < ITERS; ++k) {
        const u64 tgt = (u64)k + 1;

        // ---- phase 2: block b reduces columns [16b, 16b+16) ----
        if (lane < 16)
            poll_eq(flag1 + (size_t)(16 * wave + lane) * 8, tgt);
        asm volatile("" ::: "memory");
        {
            const int blk = 16 * wave + (lane >> 2);     // source block
            const int q   = lane & 3;                    // quad within 16 cols
            const float* cp = colpart + (size_t)blk * NN + (b << 4) + 4 * q;
            float2 a01 = ld_atomic_f32x2(cp);
            float2 a23 = ld_atomic_f32x2(cp + 2);
            f32x4 v; v.x = a01.x; v.y = a01.y; v.z = a23.x; v.w = a23.y;
            #pragma unroll
            for (int m = 4; m <= 32; m <<= 1) {          // fold 16 blocks
                v.x += __shfl_xor(v.x, m, 64);
                v.y += __shfl_xor(v.y, m, 64);
                v.z += __shfl_xor(v.z, m, 64);
                v.w += __shfl_xor(v.w, m, 64);
            }
            if (lane < 4) wql[wave * 4 + lane] = v;      // lane == q
        }
        __syncthreads();                                 // (A) wql complete
        if (wave == 0) {
            f32x4 u = wql[lane];                         // lane = w'*4 + q
            #pragma unroll
            for (int m = 4; m <= 32; m <<= 1) {          // fold 16 waves
                u.x += __shfl_xor(u.x, m, 64);
                u.y += __shfl_xor(u.y, m, 64);
                u.z += __shfl_xor(u.z, m, 64);
                u.w += __shfl_xor(u.w, m, 64);
            }
            if (lane < 4) {
                float* co = col_out + (b << 4) + 4 * lane;
                st_atomic_f32x2(co,     u.x, u.y);
                st_atomic_f32x2(co + 2, u.z, u.w);
            }
            asm volatile("s_waitcnt vmcnt(0)" ::: "memory");
            if (lane == 0) set_flag(flag2 + (size_t)b * 8, tgt);
        }

        // ---- phase 3: own 4 column sums (producer = block t>>2) ----
        if (lane < 16)
            poll_eq(flag2 + (size_t)(16 * wave + lane) * 8, tgt);
        asm volatile("" ::: "memory");
        float2 ab = ld_atomic_f32x2(col_out + 4 * t);
        float2 cd = ld_atomic_f32x2(col_out + 4 * t + 2);
        f32x4 cv; cv.x = ab.x; cv.y = ab.y; cv.z = cd.x; cv.w = cd.y;
        {   // redundant grand total (identical fold order in every block)
            float cs = (cv.x + cv.y) + (cv.z + cv.w);
            #pragma unroll
            for (int m = 1; m < 64; m <<= 1) cs += __shfl_xor(cs, m, 64);
            if (lane == 0) sred[wave] = cs;
        }
        __syncthreads();                                 // (B) sred+rowsum ready
        float s = 0.f;
        #pragma unroll
        for (int w = 0; w < 16; ++w) s += sred[w];

        const float c0 = INV_N + s * (INV_N * INV_N);
        const f32x4 csub = cv * INV_N;

        if (k + 1 < ITERS) {
            // ---- fused: relu-update + next-iter column/row partials ----
            f32x4 cacc = {0.f, 0.f, 0.f, 0.f};
            #pragma unroll
            for (int r = 0; r < RPB; ++r) {
                const float a = c0 - rowsum[r] * INV_N;
                x[r].x = fmaxf(x[r].x + a - csub.x, 0.f);
                x[r].y = fmaxf(x[r].y + a - csub.y, 0.f);
                x[r].z = fmaxf(x[r].z + a - csub.z, 0.f);
                x[r].w = fmaxf(x[r].w + a - csub.w, 0.f);
                cacc += x[r];
            }
            float* cp = colpart + (size_t)b * NN + 4 * t;
            st_atomic_f32x2(cp,     cacc.x, cacc.y);
            st_atomic_f32x2(cp + 2, cacc.z, cacc.w);
            #pragma unroll
            for (int r = 0; r < RPB; ++r)
                part[t * PSTR + r] = (x[r].x + x[r].y) + (x[r].z + x[r].w);
            asm volatile("s_waitcnt vmcnt(0)" ::: "memory");  // own stores
            __syncthreads();                             // (C) all drained +
            if (t == 0) set_flag(flag1 + (size_t)b * 8, tgt + 1);  // part ready
            float v = 0.f;
            #pragma unroll
            for (int kk = 0; kk < 16; ++kk)
                v += part[(lane + 64 * kk) * PSTR + wave];
            #pragma unroll
            for (int m = 1; m < 64; m <<= 1) v += __shfl_xor(v, m, 64);
            if (lane == 0) rowsum[wave] = v;
            // rowsum visibility covered by next iteration's sync (A)/(B)
        } else {
            #pragma unroll
            for (int r = 0; r < RPB; ++r) {
                const float a = c0 - rowsum[r] * INV_N;
                x[r].x = fmaxf(x[r].x + a - csub.x, 0.f);
                x[r].y = fmaxf(x[r].y + a - csub.y, 0.f);
                x[r].z = fmaxf(x[r].z + a - csub.z, 0.f);
                x[r].w = fmaxf(x[r].w + a - csub.w, 0.f);
            }
        }
    }

    // Final store (plain cached path).
    f32x4* xo = (f32x4*)Xout;
    #pragma unroll
    for (int r = 0; r < RPB; ++r)
        xo[(size_t)(row0 + r) * NV4 + t] = x[r];
}

extern "C" void kernel_launch(void* const* d_in, const int* in_sizes, int n_in,
                              void* d_out, int out_size, void* d_ws, size_t ws_size,
                              hipStream_t stream)
{
    const float* X0 = (const float*)d_in[0];
    float* X = (float*)d_out;

    // ws layout: colpart[256*4096] f32 (4 MB) | col_out[4096] f32 (16 KB) |
    //            flag1[256*8] u64 (16 KB) | flag2[256*8] u64 (16 KB)
    // NO initialization needed: data reads are flag-gated, and flags use
    // equality polls (harness 0xAA poison matches no target value 1..21).
    float* colpart = (float*)d_ws;
    float* col_out = colpart + (size_t)NBLK * NN;
    u64*   flag1   = (u64*)(col_out + NN);
    u64*   flag2   = flag1 + NBLK * 8;

    // Regular launch: 84 KB LDS + 16 waves -> exactly 1 block/CU,
    // grid == CU count -> all blocks co-resident (no CG API needed).
    persist10<<<dim3(NBLK), dim3(1024), 0, stream>>>(X0, X, colpart, col_out,
                                                     flag1, flag2);
}

// Round 12
// 441.400 us; speedup vs baseline: 1.4876x; 1.4876x over previous
//
#include <hip/hip_runtime.h>

// Frobenius_71975061946522 — R12: exact R9 sync skeleton + fused staging.
//
// X (4096x4096 fp32, 64 MB) lives in the unified VGPR/AGPR file for all 20
// iterations: 256 blocks x 1024 threads (1 block/CU, forced by 84 KB LDS);
// thread t of block b holds X[16b+r][4t..4t+3], r=0..15.
//
// R10+R11 lesson (twice-burned): publish flags ONLY after a block-wide
// __syncthreads. Early/per-wave publishes turn barrier-parked waves into
// spin-polling waves whose coherent loads storm the TCC and throttle the
// producers (FETCH 120->880 MB, 3x slowdown). R9's structure — poll, work,
// sync(A), fold, sync(B), publish — keeps the grid in lockstep; restored
// verbatim here.
//
// Single change vs R9 (isolated): phase-1 staging is fused into the tail of
// phase 3 — one pass over x[] computes relu-update + column partials + row
// partials, then colpart stores, wave drain, sync(C), flag1 publish, rowsum
// fold. Saves one full x[] pass + one __syncthreads per iteration. Staging
// count unchanged (prologue stages iter 0; last iteration skips dead work).
//
// WAR safety (single-buffered colpart/col_out, monotone flags, as R9):
//  - colpart[b] rewritten for k+1 only after phase3-k's flag2 poll: flag2[s]
//    >= k+1 for ALL s means every block finished its phase2-k colpart reads
//    (sync(A)-ordered before the publish).
//  - col_out[16b..) rewritten at k+1 only after b's phase2-(k+1) poll saw
//    ALL flag1 >= k+2, each published after that block's phase3-k col_out
//    reads in program order.

#define NN    4096
#define NV4   1024
#define RPB   16
#define NBLK  256
#define ITERS 20
#define INV_N (1.0f / 4096.0f)
#define PSTR  21            // part[] stride: odd (conflict-free), 84 KB LDS
                            // forces exactly 1 block/CU

typedef unsigned long long u64;
typedef float f32x4 __attribute__((ext_vector_type(4)));

__device__ __forceinline__ void st_atomic_f32x2(float* p, float a, float b) {
    u64 u = (u64)__float_as_uint(a) | ((u64)__float_as_uint(b) << 32);
    __hip_atomic_store((u64*)p, u, __ATOMIC_RELAXED, __HIP_MEMORY_SCOPE_AGENT);
}
__device__ __forceinline__ float2 ld_atomic_f32x2(const float* p) {
    u64 u = __hip_atomic_load((const u64*)p, __ATOMIC_RELAXED,
                              __HIP_MEMORY_SCOPE_AGENT);
    return make_float2(__uint_as_float((unsigned)u),
                       __uint_as_float((unsigned)(u >> 32)));
}
__device__ __forceinline__ void set_flag(u64* f, u64 v) {
    __hip_atomic_store(f, v, __ATOMIC_RELAXED, __HIP_MEMORY_SCOPE_AGENT);
}
// Lanes 0..15 poll flags[16*wave + lane] (64 B apart) until >= tgt.
__device__ __forceinline__ void wait_flags(const u64* flags, int wave, int lane, u64 tgt) {
    if (lane < 16) {
        const u64* f = flags + (size_t)(wave * 16 + lane) * 8;
        while (__hip_atomic_load(f, __ATOMIC_RELAXED, __HIP_MEMORY_SCOPE_AGENT) < tgt)
            __builtin_amdgcn_s_sleep(1);
    }
    asm volatile("" ::: "memory");   // no hoisting across the poll
}

__global__ __launch_bounds__(1024, 4)
void persist11(const float* __restrict__ X0, float* __restrict__ Xout,
               float* __restrict__ colpart,   // [NBLK][NN]
               float* __restrict__ col_out,   // [NN]
               u64* __restrict__ flag1,       // [NBLK] stride 8 (64 B)
               u64* __restrict__ flag2)       // [NBLK] stride 8
{
    const int t    = threadIdx.x;
    const int wave = t >> 6;
    const int lane = t & 63;
    const int b    = blockIdx.x;
    const int row0 = b * RPB;

    __shared__ float part[1024 * PSTR];      // row-partial transpose (~84 KB)
    __shared__ f32x4 wql[64];                // per-wave column-partial quads
    __shared__ float rowsum[RPB];
    __shared__ float sred[16];

    // Load this thread's 16 float4 of X into registers.
    f32x4 x[RPB];
    const f32x4* x0 = (const f32x4*)X0;
    #pragma unroll
    for (int r = 0; r < RPB; ++r)
        x[r] = x0[(size_t)(row0 + r) * NV4 + t];

    // ---- prologue: stage iter-0 column/row partials (== R9 phase 1) ----
    {
        f32x4 cacc = x[0];
        #pragma unroll
        for (int r = 1; r < RPB; ++r) cacc += x[r];
        float* cp = colpart + (size_t)b * NN + 4 * t;
        st_atomic_f32x2(cp,     cacc.x, cacc.y);
        st_atomic_f32x2(cp + 2, cacc.z, cacc.w);
        #pragma unroll
        for (int r = 0; r < RPB; ++r)
            part[t * PSTR + r] = (x[r].x + x[r].y) + (x[r].z + x[r].w);
        asm volatile("s_waitcnt vmcnt(0)" ::: "memory");  // own stores drained
        __syncthreads();                                   // all waves drained
        if (t == 0) set_flag(flag1 + (size_t)b * 8, 1);
        float v = 0.f;
        #pragma unroll
        for (int kk = 0; kk < 16; ++kk)
            v += part[(lane + 64 * kk) * PSTR + wave];
        #pragma unroll
        for (int m = 1; m < 64; m <<= 1) v += __shfl_xor(v, m, 64);
        if (lane == 0) rowsum[wave] = v;
        // rowsum visibility for phase 3 is covered by sync (A)/(B) below
    }

    for (unsigned k = 0; k < ITERS; ++k) {
        const u64 tgt = (u64)k + 1;

        // ---- phase 2: block b reduces columns [16b, 16b+16) (== R9) ----
        wait_flags(flag1, wave, lane, tgt);
        {
            const int blk = 16 * wave + (lane >> 2);     // source block
            const int q   = lane & 3;                    // quad within 16 cols
            const float* cp = colpart + (size_t)blk * NN + (b << 4) + 4 * q;
            float2 a01 = ld_atomic_f32x2(cp);
            float2 a23 = ld_atomic_f32x2(cp + 2);
            f32x4 v; v.x = a01.x; v.y = a01.y; v.z = a23.x; v.w = a23.y;
            #pragma unroll
            for (int m = 4; m <= 32; m <<= 1) {          // fold 16 blocks
                v.x += __shfl_xor(v.x, m, 64);
                v.y += __shfl_xor(v.y, m, 64);
                v.z += __shfl_xor(v.z, m, 64);
                v.w += __shfl_xor(v.w, m, 64);
            }
            if (lane < 4) wql[wave * 4 + lane] = v;      // lane == q
        }
        __syncthreads();                                 // (A) wql complete
        if (wave == 0) {
            f32x4 u = wql[lane];                         // lane = w'*4 + q
            #pragma unroll
            for (int m = 4; m <= 32; m <<= 1) {          // fold 16 waves
                u.x += __shfl_xor(u.x, m, 64);
                u.y += __shfl_xor(u.y, m, 64);
                u.z += __shfl_xor(u.z, m, 64);
                u.w += __shfl_xor(u.w, m, 64);
            }
            if (lane < 4) {
                float* co = col_out + (b << 4) + 4 * lane;
                st_atomic_f32x2(co,     u.x, u.y);
                st_atomic_f32x2(co + 2, u.z, u.w);
            }
            asm volatile("s_waitcnt vmcnt(0)" ::: "memory");
        }
        __syncthreads();                                 // (B) park waves here
        if (t == 0) set_flag(flag2 + (size_t)b * 8, tgt);

        // ---- phase 3: own 4 column sums (producer = block t>>2) (== R9) ----
        wait_flags(flag2, wave, lane, tgt);
        float2 ab = ld_atomic_f32x2(col_out + 4 * t);
        float2 cd = ld_atomic_f32x2(col_out + 4 * t + 2);
        f32x4 cv; cv.x = ab.x; cv.y = ab.y; cv.z = cd.x; cv.w = cd.y;
        {   // redundant grand total (identical fold order in every block)
            float cs = (cv.x + cv.y) + (cv.z + cv.w);
            #pragma unroll
            for (int m = 1; m < 64; m <<= 1) cs += __shfl_xor(cs, m, 64);
            if (lane == 0) sred[wave] = cs;
        }
        __syncthreads();                                 // sred + rowsum ready
        float s = 0.f;
        #pragma unroll
        for (int w = 0; w < 16; ++w) s += sred[w];

        const float c0 = INV_N + s * (INV_N * INV_N);
        const f32x4 csub = cv * INV_N;

        if (k + 1 < ITERS) {
            // ---- fused: relu-update + next-iter column/row partials ----
            f32x4 cacc = {0.f, 0.f, 0.f, 0.f};
            #pragma unroll
            for (int r = 0; r < RPB; ++r) {
                const float a = c0 - rowsum[r] * INV_N;
                x[r].x = fmaxf(x[r].x + a - csub.x, 0.f);
                x[r].y = fmaxf(x[r].y + a - csub.y, 0.f);
                x[r].z = fmaxf(x[r].z + a - csub.z, 0.f);
                x[r].w = fmaxf(x[r].w + a - csub.w, 0.f);
                cacc += x[r];
                part[t * PSTR + r] = (x[r].x + x[r].y) + (x[r].z + x[r].w);
            }
            float* cp = colpart + (size_t)b * NN + 4 * t;
            st_atomic_f32x2(cp,     cacc.x, cacc.y);
            st_atomic_f32x2(cp + 2, cacc.z, cacc.w);
            asm volatile("s_waitcnt vmcnt(0)" ::: "memory");  // own stores
            __syncthreads();                             // (C) all drained,
            if (t == 0) set_flag(flag1 + (size_t)b * 8, tgt + 1);  // part ready
            float v = 0.f;
            #pragma unroll
            for (int kk = 0; kk < 16; ++kk)
                v += part[(lane + 64 * kk) * PSTR + wave];
            #pragma unroll
            for (int m = 1; m < 64; m <<= 1) v += __shfl_xor(v, m, 64);
            if (lane == 0) rowsum[wave] = v;
            // rowsum visibility covered by next iteration's sync (A)/(B)
        } else {
            #pragma unroll
            for (int r = 0; r < RPB; ++r) {
                const float a = c0 - rowsum[r] * INV_N;
                x[r].x = fmaxf(x[r].x + a - csub.x, 0.f);
                x[r].y = fmaxf(x[r].y + a - csub.y, 0.f);
                x[r].z = fmaxf(x[r].z + a - csub.z, 0.f);
                x[r].w = fmaxf(x[r].w + a - csub.w, 0.f);
            }
        }
    }

    // Final store (plain cached path).
    f32x4* xo = (f32x4*)Xout;
    #pragma unroll
    for (int r = 0; r < RPB; ++r)
        xo[(size_t)(row0 + r) * NV4 + t] = x[r];
}

extern "C" void kernel_launch(void* const* d_in, const int* in_sizes, int n_in,
                              void* d_out, int out_size, void* d_ws, size_t ws_size,
                              hipStream_t stream)
{
    const float* X0 = (const float*)d_in[0];
    float* X = (float*)d_out;

    // ws layout: colpart[256*4096] f32 (4 MB) | col_out[4096] f32 (16 KB) |
    //            flag1[256*8] u64 (16 KB) | flag2[256*8] u64 (16 KB)
    float* colpart = (float*)d_ws;
    float* col_out = colpart + (size_t)NBLK * NN;
    u64*   flag1   = (u64*)(col_out + NN);
    u64*   flag2   = flag1 + NBLK * 8;

    // Zero ONLY the flags (0xAA poison would satisfy the >= polls).
    hipMemsetAsync((void*)flag1, 0, 2 * NBLK * 8 * sizeof(u64), stream);

    // Regular launch: 84 KB LDS + 16 waves -> exactly 1 block/CU,
    // grid == CU count -> all blocks co-resident (no CG API needed).
    persist11<<<dim3(NBLK), dim3(1024), 0, stream>>>(X0, X, colpart, col_out,
                                                     flag1, flag2);
}